// Round 11
// baseline (237.773 us; speedup 1.0000x reference)
//
#include <hip/hip_runtime.h>
#include <hip/hip_bf16.h>
#include <math.h>

#define B_   4
#define S_   2048
#define DIN  1024
#define DATT 1024
#define DHID 1024

typedef short bf16x8 __attribute__((ext_vector_type(8)));
typedef float f32x4  __attribute__((ext_vector_type(4)));

__device__ inline unsigned short f2bf(float f) {
    unsigned u = __float_as_uint(f);
    u += 0x7fffu + ((u >> 16) & 1u);
    return (unsigned short)(u >> 16);
}
__device__ inline float bf2f(unsigned u16) {
    return __uint_as_float(u16 << 16);
}
__device__ inline void gld16(const void* g, void* l) {
    __builtin_amdgcn_global_load_lds(
        (const __attribute__((address_space(1))) unsigned int*)g,
        (__attribute__((address_space(3))) unsigned int*)l, 16, 0, 0);
}

// XCD-aware chunked remap: each XCD gets a contiguous run of 4(bx)x2(by) chunks
__device__ inline void xmap(int& bx, int& by, int& z)
{
    int gx = gridDim.x, gy = gridDim.y;
    int nwg = gx * gy * gridDim.z;
    int lin = blockIdx.x + gx * (blockIdx.y + gy * blockIdx.z);
    int s = (nwg & 7) ? lin : ((lin & 7) * (nwg >> 3) + (lin >> 3));
    if (!(gx & 3) && !(gy & 1)) {
        int cpz = (gx >> 2) * (gy >> 1);
        int chunk = s >> 3, w = s & 7;
        int cz = chunk / cpz, c2 = chunk % cpz;
        int cx = c2 % (gx >> 2), cy = c2 / (gx >> 2);
        bx = cx * 4 + (w & 3);
        by = cy * 2 + (w >> 2);
        z  = cz;
    } else {
        bx = s % gx;
        int t = s / gx;
        by = t % gy;
        z  = t / gy;
    }
}

// ---------------- merged prep: xcvt + wcvt + mpack ----------------
__global__ __launch_bounds__(256)
void prep_k(const float* __restrict__ x, unsigned short* __restrict__ xb,
            const float* __restrict__ Wq, const float* __restrict__ Wk,
            const float* __restrict__ Wv, unsigned short* __restrict__ Wt,
            const int* __restrict__ m, unsigned* __restrict__ mb)
{
    const int b = blockIdx.x;
    const int tid = threadIdx.x;
    if (b < 4096) {
        int i = b * 256 + tid;
        const float4* p = (const float4*)x + (size_t)i * 2;
        float4 v0 = p[0], v1 = p[1];
        uint4 o;
        o.x = (unsigned)f2bf(v0.x) | ((unsigned)f2bf(v0.y) << 16);
        o.y = (unsigned)f2bf(v0.z) | ((unsigned)f2bf(v0.w) << 16);
        o.z = (unsigned)f2bf(v1.x) | ((unsigned)f2bf(v1.y) << 16);
        o.w = (unsigned)f2bf(v1.z) | ((unsigned)f2bf(v1.w) << 16);
        ((uint4*)xb)[i] = o;
    } else if (b < 4864) {
        int idx = b - 4096;
        int w = idx >> 8;
        const float* W = (w == 0) ? Wq : ((w == 1) ? Wk : Wv);
        unsigned short* D = Wt + (size_t)w * DIN * DATT;
        int t = (idx & 255) * 256 + tid;
        int n  = t >> 6;
        int kc = (t & 63) * 16;
        unsigned short r[16];
#pragma unroll
        for (int i = 0; i < 16; ++i) r[i] = f2bf(W[(size_t)(kc + i) * DATT + n]);
        uint4 o0, o1;
        o0.x = (unsigned)r[0] | ((unsigned)r[1] << 16);  o0.y = (unsigned)r[2] | ((unsigned)r[3] << 16);
        o0.z = (unsigned)r[4] | ((unsigned)r[5] << 16);  o0.w = (unsigned)r[6] | ((unsigned)r[7] << 16);
        o1.x = (unsigned)r[8] | ((unsigned)r[9] << 16);  o1.y = (unsigned)r[10] | ((unsigned)r[11] << 16);
        o1.z = (unsigned)r[12] | ((unsigned)r[13] << 16); o1.w = (unsigned)r[14] | ((unsigned)r[15] << 16);
        *(uint4*)(D + (size_t)n * DIN + kc)     = o0;
        *(uint4*)(D + (size_t)n * DIN + kc + 8) = o1;
    } else {
        int w = (b - 4864) * 256 + tid;
        const uint4* p = (const uint4*)(m + (size_t)w * 32);
        unsigned bits = 0;
#pragma unroll
        for (int g = 0; g < 8; ++g) {
            uint4 v = p[g];
            bits |= (v.x ? 1u : 0u) << (g * 4 + 0);
            bits |= (v.y ? 1u : 0u) << (g * 4 + 1);
            bits |= (v.z ? 1u : 0u) << (g * 4 + 2);
            bits |= (v.w ? 1u : 0u) << (g * 4 + 3);
        }
        mb[w] = bits;
    }
}

// ======== gemmD: 256x128 tile, BK=64, DOUBLE-buffer 96KB, counted vmcnt(6) ========
// Same math/swizzle/epilogues as the proven gemmS; only the K-loop sync changes:
// raw s_barrier + vmcnt(6) lets the next tile's 6 global_load_lds stay in flight
// through the compute phase (never drains to 0 mid-loop).
// EPI: 6 = fused QKV (Q/K bf16+bias; V gelu+bias transposed to Cp2)
//      4 = e = exp(val*scale), bitmask->0, bf16
template<int EPI>
__global__ __launch_bounds__(512, 2)
void gemmD_k(const unsigned short* __restrict__ Ap, const unsigned short* __restrict__ Bp,
             const float* __restrict__ b0, const float* __restrict__ b1,
             const float* __restrict__ b2, const unsigned* __restrict__ mbits,
             void* __restrict__ Cp, void* __restrict__ Cp2,
             int K, int lda, int ldb, int ldc,
             long aStride, long bStride, long cStride, float scale)
{
    __shared__ __align__(16) unsigned short Al[2][256][64];   // 64 KB
    __shared__ __align__(16) unsigned short Bl[2][128][64];   // 32 KB

    int bx, by, z;
    xmap(bx, by, z);
    const int tid  = threadIdx.x;
    const int row0 = by * 256;
    const int col0 = bx * 128;
    const int wid  = tid >> 6, lane = tid & 63;
    const int lr = lane & 15, lg = lane >> 4;
    const int wm = wid >> 1, wn = wid & 1;          // 4 x 2 wave grid
    const int wb = (tid & 448) * 16;                // wave-uniform LDS stage base

    const unsigned short* Ab = Ap + (size_t)aStride * z;
    const unsigned short* Bb = Bp + (size_t)bStride * z;

    f32x4 acc[4][4] = {};
    const int nt = K >> 6;

    const int srow = tid >> 3, sj = tid & 7;

    auto stage = [&](int b, int t) {
        const int k0 = t << 6;
#pragma unroll
        for (int r = 0; r < 4; ++r) {
            int row = r * 64 + srow;
            gld16(Ab + (size_t)(row0 + row) * lda + k0 + ((sj ^ (row & 7)) << 3),
                  (char*)&Al[b][0][0] + r * 8192 + wb);
        }
#pragma unroll
        for (int r = 0; r < 2; ++r) {
            int row = r * 64 + srow;
            gld16(Bb + (size_t)(col0 + row) * ldb + k0 + ((sj ^ (row & 7)) << 3),
                  (char*)&Bl[b][0][0] + r * 8192 + wb);
        }
    };

    stage(0, 0);                                    // 6 loads in flight
    for (int t = 0; t < nt; ++t) {
        const int cur = t & 1;
        if (t + 1 < nt) {
            stage(cur ^ 1, t + 1);                  // +6 → 12 outstanding
            asm volatile("s_waitcnt vmcnt(6)" ::: "memory");   // tile t retired; t+1 flies
        } else {
            asm volatile("s_waitcnt vmcnt(0)" ::: "memory");   // final tile drain
        }
        __builtin_amdgcn_s_barrier();               // collective: all waves' t-loads done
        const char* baseA = (const char*)&Al[cur][0][0];
        const char* baseB = (const char*)&Bl[cur][0][0];
#pragma unroll
        for (int s = 0; s < 2; ++s) {
            bf16x8 av[4], bv[4];
#pragma unroll
            for (int i = 0; i < 4; ++i) {
                int ra = wm * 64 + i * 16 + lr;
                av[i] = *(const bf16x8*)(baseA + ra * 128 + ((((s << 2) | lg) ^ (ra & 7)) << 4));
                int rb = wn * 64 + i * 16 + lr;
                bv[i] = *(const bf16x8*)(baseB + rb * 128 + ((((s << 2) | lg) ^ (rb & 7)) << 4));
            }
#pragma unroll
            for (int mi = 0; mi < 4; ++mi)
#pragma unroll
                for (int ni = 0; ni < 4; ++ni)
                    acc[mi][ni] = __builtin_amdgcn_mfma_f32_16x16x32_bf16(av[mi], bv[ni], acc[mi][ni], 0, 0, 0);
        }
        __builtin_amdgcn_s_barrier();               // reads of buf cur done → reusable
    }

    // per-wave scratch in Al[0] region (after final drain+barrier all LDS traffic done)
    unsigned short* scr = &Al[0][0][0] + wid * 2048;   // 4KB/wave, 8 waves = 32KB

    if (EPI == 6) {
        int w = col0 >> 10;
        if (w < 2) {
            // Q/K: normal layout, coalesced via transpose
            unsigned short* C = (unsigned short*)Cp + (size_t)w * ((size_t)B_ * S_ * DATT);
            const float* bias = w ? b1 : b0;
            int cb0 = (col0 & 1023) + wn * 64;
#pragma unroll
            for (int h = 0; h < 2; ++h) {
#pragma unroll
                for (int mm = 0; mm < 2; ++mm) {
                    int mi = h * 2 + mm;
#pragma unroll
                    for (int ni = 0; ni < 4; ++ni) {
                        int lcol = ni * 16 + lr;
                        float bb = bias[cb0 + lcol];
#pragma unroll
                        for (int v = 0; v < 4; ++v) {
                            int wrow = mm * 16 + lg * 4 + v;
                            scr[wrow * 64 + (((lcol >> 3) ^ (wrow & 7)) << 3) + (lcol & 7)] =
                                f2bf(acc[mi][ni][v] + bb);
                        }
                    }
                }
                asm volatile("s_waitcnt lgkmcnt(0)" ::: "memory");
#pragma unroll
                for (int rr = 0; rr < 4; ++rr) {
                    int lrow = rr * 8 + (lane >> 3);
                    int chunk = lane & 7;
                    uint4 u = *(const uint4*)&scr[lrow * 64 + ((chunk ^ (lrow & 7)) << 3)];
                    int grow = row0 + wm * 64 + h * 32 + lrow;
                    *(uint4*)(C + (size_t)grow * DATT + cb0 + chunk * 8) = u;
                }
                asm volatile("s_waitcnt lgkmcnt(0)" ::: "memory");
            }
        } else {
            // V: gelu + transposed out C2[(zz*DHID + hid)*S + s]; transpose by hid halves
            unsigned short* C = (unsigned short*)Cp2;
            int zz = row0 >> 11;
            int sb0 = (row0 & 2047) + wm * 64;
            int hb0 = (col0 & 1023) + wn * 64;
#pragma unroll
            for (int h = 0; h < 2; ++h) {
#pragma unroll
                for (int nn = 0; nn < 2; ++nn) {
                    int ni = h * 2 + nn;
                    int lcol = nn * 16 + lr;                      // local hid 0..31
                    float bb = b2[hb0 + h * 32 + lcol];
#pragma unroll
                    for (int mi = 0; mi < 4; ++mi)
#pragma unroll
                        for (int v = 0; v < 4; ++v) {
                            int lrow = mi * 16 + lg * 4 + v;      // local s 0..63
                            float xv = acc[mi][ni][v] + bb;
                            xv = 0.5f * xv * (1.0f + erff(xv * 0.70710678118654752f));
                            scr[lcol * 64 + (((lrow >> 3) ^ (lcol & 7)) << 3) + (lrow & 7)] = f2bf(xv);
                        }
                }
                asm volatile("s_waitcnt lgkmcnt(0)" ::: "memory");
#pragma unroll
                for (int rr = 0; rr < 4; ++rr) {
                    int lhid = rr * 8 + (lane >> 3);              // 0..31
                    int chunk = lane & 7;
                    uint4 u = *(const uint4*)&scr[lhid * 64 + ((chunk ^ (lhid & 7)) << 3)];
                    int ghid = hb0 + h * 32 + lhid;
                    *(uint4*)(C + ((size_t)zz * DHID + ghid) * S_ + sb0 + chunk * 8) = u;
                }
                asm volatile("s_waitcnt lgkmcnt(0)" ::: "memory");
            }
        }
    } else {  // EPI == 4: e = bit ? 0 : exp(acc*scale), coalesced via transpose
        unsigned short* C = (unsigned short*)Cp + (size_t)cStride * z;
        const unsigned* mb = mbits + (size_t)z * (S_ * S_ / 32);
        const int wbase = (col0 + wn * 64) >> 5;
#pragma unroll
        for (int h = 0; h < 2; ++h) {
#pragma unroll
            for (int mm = 0; mm < 2; ++mm) {
                int mi = h * 2 + mm;
#pragma unroll
                for (int v = 0; v < 4; ++v) {
                    int row = row0 + wm * 64 + mi * 16 + lg * 4 + v;
                    unsigned w0 = mb[(size_t)row * (S_ / 32) + wbase];
                    unsigned w1 = mb[(size_t)row * (S_ / 32) + wbase + 1];
                    int wrow = mm * 16 + lg * 4 + v;
#pragma unroll
                    for (int ni = 0; ni < 4; ++ni) {
                        int lcol = ni * 16 + lr;
                        unsigned wsel = (ni & 2) ? w1 : w0;
                        float ev = ((wsel >> ((ni & 1) * 16 + lr)) & 1)
                                 ? 0.0f : __expf(acc[mi][ni][v] * scale);
                        scr[wrow * 64 + (((lcol >> 3) ^ (wrow & 7)) << 3) + (lcol & 7)] = f2bf(ev);
                    }
                }
            }
            asm volatile("s_waitcnt lgkmcnt(0)" ::: "memory");
#pragma unroll
            for (int rr = 0; rr < 4; ++rr) {
                int lrow = rr * 8 + (lane >> 3);
                int chunk = lane & 7;
                uint4 u = *(const uint4*)&scr[lrow * 64 + ((chunk ^ (lrow & 7)) << 3)];
                int grow = row0 + wm * 64 + h * 32 + lrow;
                *(uint4*)(C + (size_t)grow * ldc + col0 + wn * 64 + chunk * 8) = u;
            }
            asm volatile("s_waitcnt lgkmcnt(0)" ::: "memory");
        }
    }
}

// ================== 128^2 dbuf GEMM (R3-proven) + chunked swizzle ==================
// EPI: 6 fused QKV, 2 fp32 scale+mask, 3 fp32, 5 fp32*invs[row]
template<int AMODE, int EPI>
__global__ __launch_bounds__(256)
void gemm_k(const void* __restrict__ Ap, const unsigned short* __restrict__ Bp,
            const float* __restrict__ b0, const float* __restrict__ b1,
            const float* __restrict__ b2, const int* __restrict__ maskp,
            void* __restrict__ Cp, void* __restrict__ Cp2,
            int K, int lda, int ldb, int ldc,
            long aStride, long bStride, long cStride, long mStride, float scale)
{
    __shared__ __align__(16) unsigned short sh[2][2][128][64];
    int bx, by, z;
    xmap(bx, by, z);
    const int tid  = threadIdx.x;
    const int row0 = by * 128;
    const int col0 = bx * 128;
    const int wave = tid >> 6, lane = tid & 63;
    const int lr = lane & 15, lg = lane >> 4;
    const int wm = (wave >> 1) * 64, wn = (wave & 1) * 64;
    const unsigned short* Bb = Bp + (size_t)bStride * z;
    f32x4 acc[4][4] = {};
    const int nt = K >> 6;
    auto stage = [&](int b, int k0) {
        if (AMODE == 0) {
            const unsigned short* A = (const unsigned short*)Ap + (size_t)aStride * z;
#pragma unroll
            for (int q = 0; q < 4; ++q) {
                int c = q * 256 + tid;
                int row = c >> 3, j = c & 7;
                gld16((const char*)(A + (size_t)(row0 + row) * lda + k0) + ((j ^ (row & 7)) << 4),
                      (char*)&sh[b][0][0][0] + ((q * 256 + (tid & 192)) << 4));
            }
        } else {
            const float* A = (const float*)Ap + (size_t)aStride * z;
#pragma unroll
            for (int q = 0; q < 4; ++q) {
                int c = q * 256 + tid;
                int row = c >> 3, j = c & 7;
                const float* src = A + (size_t)(row0 + row) * lda + k0 + ((j ^ (row & 7)) << 3);
                float4 v0 = *(const float4*)src;
                float4 v1 = *(const float4*)(src + 4);
                uint4 p;
                p.x = (unsigned)f2bf(v0.x) | ((unsigned)f2bf(v0.y) << 16);
                p.y = (unsigned)f2bf(v0.z) | ((unsigned)f2bf(v0.w) << 16);
                p.z = (unsigned)f2bf(v1.x) | ((unsigned)f2bf(v1.y) << 16);
                p.w = (unsigned)f2bf(v1.z) | ((unsigned)f2bf(v1.w) << 16);
                *(uint4*)((char*)&sh[b][0][0][0] + ((size_t)c << 4)) = p;
            }
        }
#pragma unroll
        for (int q = 0; q < 4; ++q) {
            int c = q * 256 + tid;
            int row = c >> 3, j = c & 7;
            gld16((const char*)(Bb + (size_t)(col0 + row) * ldb + k0) + ((j ^ (row & 7)) << 4),
                  (char*)&sh[b][1][0][0] + ((q * 256 + (tid & 192)) << 4));
        }
    };
    stage(0, 0);
    __syncthreads();
    int cur = 0;
    for (int t = 0; t < nt; ++t) {
        if (t + 1 < nt) stage(cur ^ 1, (t + 1) << 6);
        const char* baseA = (const char*)&sh[cur][0][0][0];
        const char* baseB = (const char*)&sh[cur][1][0][0];
        bf16x8 af[2][4], bfv[2][4];
#pragma unroll
        for (int s = 0; s < 2; ++s)
#pragma unroll
            for (int i = 0; i < 4; ++i) {
                int ra = wm + i * 16 + lr;
                af[s][i]  = *(const bf16x8*)(baseA + ra * 128 + ((((s << 2) | lg) ^ (ra & 7)) << 4));
                int rb = wn + i * 16 + lr;
                bfv[s][i] = *(const bf16x8*)(baseB + rb * 128 + ((((s << 2) | lg) ^ (rb & 7)) << 4));
            }
#pragma unroll
        for (int s = 0; s < 2; ++s)
#pragma unroll
            for (int mi = 0; mi < 4; ++mi)
#pragma unroll
                for (int ni = 0; ni < 4; ++ni)
                    acc[mi][ni] = __builtin_amdgcn_mfma_f32_16x16x32_bf16(af[s][mi], bfv[s][ni], acc[mi][ni], 0, 0, 0);
        if (t + 1 < nt) __syncthreads();
        cur ^= 1;
    }
    if (EPI == 6) {
        int w = col0 >> 10;
        int cb = (col0 & 1023) + wn;
        if (w < 2) {
            unsigned short* C = (unsigned short*)Cp + (size_t)w * ((size_t)B_ * S_ * DATT);
            const float* bias = w ? b1 : b0;
#pragma unroll
            for (int mi = 0; mi < 4; ++mi)
#pragma unroll
                for (int ni = 0; ni < 4; ++ni) {
                    int col = cb + ni * 16 + lr;
                    float bb = bias[col];
                    int rowb = row0 + wm + mi * 16 + lg * 4;
#pragma unroll
                    for (int v = 0; v < 4; ++v)
                        C[(size_t)(rowb + v) * DATT + col] = f2bf(acc[mi][ni][v] + bb);
                }
        } else {
            unsigned short* C = (unsigned short*)Cp2;
            int zz = row0 >> 11;
            int sb = (row0 & 2047) + wm;
#pragma unroll
            for (int mi = 0; mi < 4; ++mi)
#pragma unroll
                for (int ni = 0; ni < 4; ++ni) {
                    int col = cb + ni * 16 + lr;
                    float bb = b2[col];
                    unsigned short r[4];
#pragma unroll
                    for (int v = 0; v < 4; ++v) {
                        float xv = acc[mi][ni][v] + bb;
                        xv = 0.5f * xv * (1.0f + erff(xv * 0.70710678118654752f));
                        r[v] = f2bf(xv);
                    }
                    uint2 o;
                    o.x = (unsigned)r[0] | ((unsigned)r[1] << 16);
                    o.y = (unsigned)r[2] | ((unsigned)r[3] << 16);
                    *(uint2*)(C + ((size_t)zz * DHID + col) * S_ + sb + mi * 16 + lg * 4) = o;
                }
        }
    } else if (EPI == 5) {
        float* C = (float*)Cp + (size_t)cStride * z;
        const float* invs = b0 + (size_t)z * S_;
#pragma unroll
        for (int mi = 0; mi < 4; ++mi)
#pragma unroll
            for (int ni = 0; ni < 4; ++ni) {
                int col = col0 + wn + ni * 16 + lr;
                int rowb = row0 + wm + mi * 16 + lg * 4;
#pragma unroll
                for (int v = 0; v < 4; ++v)
                    C[(size_t)(rowb + v) * ldc + col] = acc[mi][ni][v] * invs[rowb + v];
            }
    } else {
        float* C = (float*)Cp + (size_t)cStride * z;
        const int* mp = (EPI == 2) ? (maskp + (size_t)mStride * z) : nullptr;
#pragma unroll
        for (int mi = 0; mi < 4; ++mi)
#pragma unroll
            for (int ni = 0; ni < 4; ++ni) {
                int col = col0 + wn + ni * 16 + lr;
                int rowb = row0 + wm + mi * 16 + lg * 4;
#pragma unroll
                for (int v = 0; v < 4; ++v) {
                    float val = acc[mi][ni][v];
                    if (EPI == 2) val = val * scale + (float)mp[(size_t)(rowb + v) * ldc + col] * (-1e9f);
                    C[(size_t)(rowb + v) * ldc + col] = val;
                }
            }
    }
}

// ------- merged rownorm: read e once -> write invs + attn fp32 -------
__global__ __launch_bounds__(256)
void rownormM_k(const unsigned short* __restrict__ e, float* __restrict__ attn,
                float* __restrict__ invs)
{
    const int row = blockIdx.x;
    const int tid = threadIdx.x;
    uint4 u = ((const uint4*)(e + (size_t)row * S_))[tid];
    float f[8];
    f[0] = bf2f(u.x & 0xffffu); f[1] = bf2f(u.x >> 16);
    f[2] = bf2f(u.y & 0xffffu); f[3] = bf2f(u.y >> 16);
    f[4] = bf2f(u.z & 0xffffu); f[5] = bf2f(u.z >> 16);
    f[6] = bf2f(u.w & 0xffffu); f[7] = bf2f(u.w >> 16);
    float s = ((f[0] + f[1]) + (f[2] + f[3])) + ((f[4] + f[5]) + (f[6] + f[7]));
#pragma unroll
    for (int o = 32; o; o >>= 1) s += __shfl_xor(s, o);
    __shared__ float red[4];
    if ((tid & 63) == 0) red[tid >> 6] = s;
    __syncthreads();
    s = (red[0] + red[1]) + (red[2] + red[3]);
    float inv = 1.0f / s;
    float* p = attn + (size_t)row * S_;
    ((float4*)p)[tid * 2]     = make_float4(f[0] * inv, f[1] * inv, f[2] * inv, f[3] * inv);
    ((float4*)p)[tid * 2 + 1] = make_float4(f[4] * inv, f[5] * inv, f[6] * inv, f[7] * inv);
    if (tid == 0) invs[row] = inv;
}

// ---------------- two-pass rownorm (mid tier) ----------------
template<bool WRITEATTN>
__global__ __launch_bounds__(256)
void rownorm_k(const unsigned short* __restrict__ e, float* __restrict__ attn,
               float* __restrict__ invs)
{
    const int row = blockIdx.x;
    const int tid = threadIdx.x;
    uint4 u = ((const uint4*)(e + (size_t)row * S_))[tid];
    float f[8];
    f[0] = bf2f(u.x & 0xffffu); f[1] = bf2f(u.x >> 16);
    f[2] = bf2f(u.y & 0xffffu); f[3] = bf2f(u.y >> 16);
    f[4] = bf2f(u.z & 0xffffu); f[5] = bf2f(u.z >> 16);
    f[6] = bf2f(u.w & 0xffffu); f[7] = bf2f(u.w >> 16);
    float s = ((f[0] + f[1]) + (f[2] + f[3])) + ((f[4] + f[5]) + (f[6] + f[7]));
#pragma unroll
    for (int o = 32; o; o >>= 1) s += __shfl_xor(s, o);
    __shared__ float red[4];
    if ((tid & 63) == 0) red[tid >> 6] = s;
    __syncthreads();
    s = (red[0] + red[1]) + (red[2] + red[3]);
    float inv = 1.0f / s;
    if (WRITEATTN) {
        float* p = attn + (size_t)row * S_;
        ((float4*)p)[tid * 2]     = make_float4(f[0] * inv, f[1] * inv, f[2] * inv, f[3] * inv);
        ((float4*)p)[tid * 2 + 1] = make_float4(f[4] * inv, f[5] * inv, f[6] * inv, f[7] * inv);
    } else {
        if (tid == 0) invs[row] = inv;
    }
}

// ---------------- fallback row softmax ----------------
__global__ __launch_bounds__(256)
void softmax_k(float* __restrict__ attn)
{
    const int row = blockIdx.x;
    float* p = attn + (size_t)row * S_;
    const int tid = threadIdx.x;
    float4 a = ((const float4*)p)[tid * 2];
    float4 b = ((const float4*)p)[tid * 2 + 1];
    float m = fmaxf(fmaxf(fmaxf(a.x, a.y), fmaxf(a.z, a.w)),
                    fmaxf(fmaxf(b.x, b.y), fmaxf(b.z, b.w)));
#pragma unroll
    for (int o = 32; o; o >>= 1) m = fmaxf(m, __shfl_xor(m, o));
    __shared__ float redm[4];
    __shared__ float reds[4];
    if ((tid & 63) == 0) redm[tid >> 6] = m;
    __syncthreads();
    m = fmaxf(fmaxf(redm[0], redm[1]), fmaxf(redm[2], redm[3]));
    float e[8];
    e[0] = expf(a.x - m); e[1] = expf(a.y - m); e[2] = expf(a.z - m); e[3] = expf(a.w - m);
    e[4] = expf(b.x - m); e[5] = expf(b.y - m); e[6] = expf(b.z - m); e[7] = expf(b.w - m);
    float s = e[0] + e[1] + e[2] + e[3] + e[4] + e[5] + e[6] + e[7];
#pragma unroll
    for (int o = 32; o; o >>= 1) s += __shfl_xor(s, o);
    if ((tid & 63) == 0) reds[tid >> 6] = s;
    __syncthreads();
    s = reds[0] + reds[1] + reds[2] + reds[3];
    float inv = 1.0f / s;
    ((float4*)p)[tid * 2]     = make_float4(e[0] * inv, e[1] * inv, e[2] * inv, e[3] * inv);
    ((float4*)p)[tid * 2 + 1] = make_float4(e[4] * inv, e[5] * inv, e[6] * inv, e[7] * inv);
}

extern "C" void kernel_launch(void* const* d_in, const int* in_sizes, int n_in,
                              void* d_out, int out_size, void* d_ws, size_t ws_size,
                              hipStream_t stream)
{
    const float* x    = (const float*)d_in[0];
    const int*   mask = (const int*)d_in[1];
    const float* Wq   = (const float*)d_in[2];
    const float* bq   = (const float*)d_in[3];
    const float* Wk   = (const float*)d_in[4];
    const float* bk   = (const float*)d_in[5];
    const float* Wv   = (const float*)d_in[6];
    const float* bv   = (const float*)d_in[7];

    float* ctx  = (float*)d_out;                       // [B,S,DHID] fp32
    float* attn = ctx + (size_t)B_ * S_ * DHID;        // [B,S,S]    fp32

    unsigned short* Qb = (unsigned short*)ctx;                 // ctx region scratch
    unsigned short* Kb = Qb + (size_t)B_ * S_ * DATT;
    unsigned short* Xb = (unsigned short*)attn;                // attn region scratch
    unsigned short* Wb = Xb + (size_t)B_ * S_ * DIN;

    const size_t eElems  = (size_t)B_ * S_ * S_;
    const size_t mWords  = eElems / 32;
    const size_t wvElems = (size_t)B_ * DHID * S_;

    size_t needFast = eElems * 2 + (size_t)B_ * S_ * 4 + mWords * 4 + wvElems * 2 + 256;
    size_t needMid  = eElems * 2 + (size_t)B_ * S_ * 4 + mWords * 4 + 256;

    dim3 blk(256), blk5(512);

    if (ws_size >= needFast) {
        unsigned short* e    = (unsigned short*)d_ws;                 // 33.55 MB
        float*          invs = (float*)(e + eElems);                  // 32 KB
        unsigned*       mb   = (unsigned*)(invs + (size_t)B_ * S_);   // 2 MB
        unsigned short* WVbT = (unsigned short*)(mb + mWords);        // 16.78 MB

        prep_k<<<dim3(6912), blk, 0, stream>>>(x, Xb, Wq, Wk, Wv, Wb, mask, mb);
        // fused QKV (256x128 tile, dbuf+vmcnt6): V gelu+T -> WVbT(ws)
        gemmD_k<6><<<dim3(24, 32, 1), blk5, 0, stream>>>(
            Xb, Wb, bq, bk, bv, nullptr, Qb, WVbT,
            DIN, DIN, DIN, 0, 0, 0, 0, 1.0f);
        // e = exp(QK^T/32), bitmask -> 0, bf16
        gemmD_k<4><<<dim3(16, 8, 4), blk5, 0, stream>>>(
            Qb, Kb, nullptr, nullptr, nullptr, mb, e, nullptr,
            DATT, DATT, DATT, S_,
            (long)S_ * DATT, (long)S_ * DATT, (long)S_ * S_, 0.03125f);
        // merged: invs + attn fp32 (Xb/Wb dead; WVbT safe in ws)
        rownormM_k<<<dim3(B_ * S_), blk, 0, stream>>>(e, attn, invs);
        // ctx = (e @ WV) * inv_rowsum (over Qb/Kb region)
        gemm_k<0, 5><<<dim3(8, 16, 4), blk, 0, stream>>>(
            e, WVbT, invs, nullptr, nullptr, nullptr, ctx, nullptr,
            S_, S_, S_, DHID,
            (long)S_ * S_, (long)DHID * S_, (long)S_ * DHID, 0, 1.0f);
    } else if (ws_size >= needMid) {
        unsigned short* e    = (unsigned short*)d_ws;
        float*          invs = (float*)(e + eElems);
        unsigned*       mb   = (unsigned*)(invs + (size_t)B_ * S_);
        unsigned short* WVbT = Wb + (size_t)3 * DIN * DATT;           // attn region

        prep_k<<<dim3(6912), blk, 0, stream>>>(x, Xb, Wq, Wk, Wv, Wb, mask, mb);
        gemmD_k<6><<<dim3(24, 32, 1), blk5, 0, stream>>>(
            Xb, Wb, bq, bk, bv, nullptr, Qb, WVbT,
            DIN, DIN, DIN, 0, 0, 0, 0, 1.0f);
        gemmD_k<4><<<dim3(16, 8, 4), blk5, 0, stream>>>(
            Qb, Kb, nullptr, nullptr, nullptr, mb, e, nullptr,
            DATT, DATT, DATT, S_,
            (long)S_ * DATT, (long)S_ * DATT, (long)S_ * S_, 0.03125f);
        rownorm_k<false><<<dim3(B_ * S_), blk, 0, stream>>>(e, nullptr, invs);
        gemm_k<0, 5><<<dim3(8, 16, 4), blk, 0, stream>>>(
            e, WVbT, invs, nullptr, nullptr, nullptr, ctx, nullptr,
            S_, S_, S_, DHID,
            (long)S_ * S_, (long)DHID * S_, (long)S_ * DHID, 0, 1.0f);
        rownorm_k<true><<<dim3(B_ * S_), blk, 0, stream>>>(e, attn, nullptr);
    } else {
        // slow tier: no ws assumptions beyond WVw
        unsigned short* WVw = (unsigned short*)d_ws;
        prep_k<<<dim3(4864), blk, 0, stream>>>(x, Xb, Wq, Wk, Wv, Wb, mask, nullptr);
        gemm_k<0, 6><<<dim3(24, 64, 1), blk, 0, stream>>>(
            Xb, Wb, bq, bk, bv, nullptr, Qb, WVw,
            DIN, DIN, DIN, 0, 0, 0, 0, 0, 1.0f);
        gemm_k<0, 2><<<dim3(16, 16, 4), blk, 0, stream>>>(
            Qb, Kb, nullptr, nullptr, nullptr, mask, attn, nullptr,
            DATT, DATT, DATT, S_,
            (long)S_ * DATT, (long)S_ * DATT, (long)S_ * S_, (long)S_ * S_, 0.03125f);
        softmax_k<<<dim3(B_ * S_), blk, 0, stream>>>(attn);
        gemm_k<1, 3><<<dim3(8, 16, 4), blk, 0, stream>>>(
            attn, WVw, nullptr, nullptr, nullptr, nullptr, ctx, nullptr,
            S_, S_, S_, DHID,
            (long)S_ * S_, (long)DHID * S_, (long)S_ * DHID, 0, 1.0f);
    }
}

// Round 12
// 210.274 us; speedup vs baseline: 1.1308x; 1.1308x over previous
//
#include <hip/hip_runtime.h>
#include <hip/hip_bf16.h>
#include <math.h>

#define B_   4
#define S_   2048
#define DIN  1024
#define DATT 1024
#define DHID 1024

typedef short bf16x8 __attribute__((ext_vector_type(8)));
typedef float f32x4  __attribute__((ext_vector_type(4)));

__device__ inline unsigned short f2bf(float f) {
    unsigned u = __float_as_uint(f);
    u += 0x7fffu + ((u >> 16) & 1u);
    return (unsigned short)(u >> 16);
}
__device__ inline float bf2f(unsigned u16) {
    return __uint_as_float(u16 << 16);
}
__device__ inline void gld16(const void* g, void* l) {
    __builtin_amdgcn_global_load_lds(
        (const __attribute__((address_space(1))) unsigned int*)g,
        (__attribute__((address_space(3))) unsigned int*)l, 16, 0, 0);
}

// XCD-aware chunked remap: each XCD gets a contiguous run of 4(bx)x2(by) chunks
__device__ inline void xmap(int& bx, int& by, int& z)
{
    int gx = gridDim.x, gy = gridDim.y;
    int nwg = gx * gy * gridDim.z;
    int lin = blockIdx.x + gx * (blockIdx.y + gy * blockIdx.z);
    int s = (nwg & 7) ? lin : ((lin & 7) * (nwg >> 3) + (lin >> 3));
    if (!(gx & 3) && !(gy & 1)) {
        int cpz = (gx >> 2) * (gy >> 1);
        int chunk = s >> 3, w = s & 7;
        int cz = chunk / cpz, c2 = chunk % cpz;
        int cx = c2 % (gx >> 2), cy = c2 / (gx >> 2);
        bx = cx * 4 + (w & 3);
        by = cy * 2 + (w >> 2);
        z  = cz;
    } else {
        bx = s % gx;
        int t = s / gx;
        by = t % gy;
        z  = t / gy;
    }
}

// ---------------- merged prep: xcvt + wcvt + mpack ----------------
__global__ __launch_bounds__(256)
void prep_k(const float* __restrict__ x, unsigned short* __restrict__ xb,
            const float* __restrict__ Wq, const float* __restrict__ Wk,
            const float* __restrict__ Wv, unsigned short* __restrict__ Wt,
            const int* __restrict__ m, unsigned* __restrict__ mb)
{
    const int b = blockIdx.x;
    const int tid = threadIdx.x;
    if (b < 4096) {
        int i = b * 256 + tid;
        const float4* p = (const float4*)x + (size_t)i * 2;
        float4 v0 = p[0], v1 = p[1];
        uint4 o;
        o.x = (unsigned)f2bf(v0.x) | ((unsigned)f2bf(v0.y) << 16);
        o.y = (unsigned)f2bf(v0.z) | ((unsigned)f2bf(v0.w) << 16);
        o.z = (unsigned)f2bf(v1.x) | ((unsigned)f2bf(v1.y) << 16);
        o.w = (unsigned)f2bf(v1.z) | ((unsigned)f2bf(v1.w) << 16);
        ((uint4*)xb)[i] = o;
    } else if (b < 4864) {
        int idx = b - 4096;
        int w = idx >> 8;
        const float* W = (w == 0) ? Wq : ((w == 1) ? Wk : Wv);
        unsigned short* D = Wt + (size_t)w * DIN * DATT;
        int t = (idx & 255) * 256 + tid;
        int n  = t >> 6;
        int kc = (t & 63) * 16;
        unsigned short r[16];
#pragma unroll
        for (int i = 0; i < 16; ++i) r[i] = f2bf(W[(size_t)(kc + i) * DATT + n]);
        uint4 o0, o1;
        o0.x = (unsigned)r[0] | ((unsigned)r[1] << 16);  o0.y = (unsigned)r[2] | ((unsigned)r[3] << 16);
        o0.z = (unsigned)r[4] | ((unsigned)r[5] << 16);  o0.w = (unsigned)r[6] | ((unsigned)r[7] << 16);
        o1.x = (unsigned)r[8] | ((unsigned)r[9] << 16);  o1.y = (unsigned)r[10] | ((unsigned)r[11] << 16);
        o1.z = (unsigned)r[12] | ((unsigned)r[13] << 16); o1.w = (unsigned)r[14] | ((unsigned)r[15] << 16);
        *(uint4*)(D + (size_t)n * DIN + kc)     = o0;
        *(uint4*)(D + (size_t)n * DIN + kc + 8) = o1;
    } else {
        int w = (b - 4864) * 256 + tid;
        const uint4* p = (const uint4*)(m + (size_t)w * 32);
        unsigned bits = 0;
#pragma unroll
        for (int g = 0; g < 8; ++g) {
            uint4 v = p[g];
            bits |= (v.x ? 1u : 0u) << (g * 4 + 0);
            bits |= (v.y ? 1u : 0u) << (g * 4 + 1);
            bits |= (v.z ? 1u : 0u) << (g * 4 + 2);
            bits |= (v.w ? 1u : 0u) << (g * 4 + 3);
        }
        mb[w] = bits;
    }
}

// ======== gemmS: 256x128 tile, BK=64, single-buffer 48KB, 8 waves 4Mx2N ========
// Coalesced bf16 epilogues: per-wave LDS transpose (scratch = Al region, 4KB/wave,
// two 32-row halves), then 128B-per-row uint4 global stores.
// EPI: 6 = fused QKV (Q/K bf16+bias; V gelu+bias transposed to Cp2)
//      4 = e = exp(val*scale), bitmask->0, bf16
template<int EPI>
__global__ __launch_bounds__(512, 4)
void gemmS_k(const unsigned short* __restrict__ Ap, const unsigned short* __restrict__ Bp,
             const float* __restrict__ b0, const float* __restrict__ b1,
             const float* __restrict__ b2, const unsigned* __restrict__ mbits,
             void* __restrict__ Cp, void* __restrict__ Cp2,
             int K, int lda, int ldb, int ldc,
             long aStride, long bStride, long cStride, float scale)
{
    __shared__ __align__(16) unsigned short Al[256][64];   // 32 KB
    __shared__ __align__(16) unsigned short Bl[128][64];   // 16 KB

    int bx, by, z;
    xmap(bx, by, z);
    const int tid  = threadIdx.x;
    const int row0 = by * 256;
    const int col0 = bx * 128;
    const int wid  = tid >> 6, lane = tid & 63;
    const int lr = lane & 15, lg = lane >> 4;
    const int wm = wid >> 1, wn = wid & 1;          // 4 x 2 wave grid
    const int wb = (tid & 448) * 16;                // wave-uniform LDS stage base

    const unsigned short* Ab = Ap + (size_t)aStride * z;
    const unsigned short* Bb = Bp + (size_t)bStride * z;

    f32x4 acc[4][4] = {};
    const int nt = K >> 6;

    const int srow = tid >> 3, sj = tid & 7;

    for (int t = 0; t < nt; ++t) {
        const int k0 = t << 6;
#pragma unroll
        for (int r = 0; r < 4; ++r) {
            int row = r * 64 + srow;
            gld16(Ab + (size_t)(row0 + row) * lda + k0 + ((sj ^ (row & 7)) << 3),
                  (char*)&Al[0][0] + r * 8192 + wb);
        }
#pragma unroll
        for (int r = 0; r < 2; ++r) {
            int row = r * 64 + srow;
            gld16(Bb + (size_t)(col0 + row) * ldb + k0 + ((sj ^ (row & 7)) << 3),
                  (char*)&Bl[0][0] + r * 8192 + wb);
        }
        __syncthreads();
#pragma unroll
        for (int s = 0; s < 2; ++s) {
            bf16x8 av[4], bv[4];
#pragma unroll
            for (int i = 0; i < 4; ++i) {
                int ra = wm * 64 + i * 16 + lr;
                av[i] = *(const bf16x8*)((const char*)&Al[0][0] + ra * 128 + ((((s << 2) | lg) ^ (ra & 7)) << 4));
                int rb = wn * 64 + i * 16 + lr;
                bv[i] = *(const bf16x8*)((const char*)&Bl[0][0] + rb * 128 + ((((s << 2) | lg) ^ (rb & 7)) << 4));
            }
#pragma unroll
            for (int mi = 0; mi < 4; ++mi)
#pragma unroll
                for (int ni = 0; ni < 4; ++ni)
                    acc[mi][ni] = __builtin_amdgcn_mfma_f32_16x16x32_bf16(av[mi], bv[ni], acc[mi][ni], 0, 0, 0);
        }
        __syncthreads();
    }

    // per-wave scratch in Al region (after trailing barrier all LDS reads are done)
    unsigned short* scr = &Al[0][0] + wid * 2048;   // 4KB/wave, 8 waves = 32KB

    if (EPI == 6) {
        int w = col0 >> 10;
        if (w < 2) {
            // Q/K: normal layout, coalesced via transpose
            unsigned short* C = (unsigned short*)Cp + (size_t)w * ((size_t)B_ * S_ * DATT);
            const float* bias = w ? b1 : b0;
            int cb0 = (col0 & 1023) + wn * 64;
#pragma unroll
            for (int h = 0; h < 2; ++h) {
#pragma unroll
                for (int mm = 0; mm < 2; ++mm) {
                    int mi = h * 2 + mm;
#pragma unroll
                    for (int ni = 0; ni < 4; ++ni) {
                        int lcol = ni * 16 + lr;
                        float bb = bias[cb0 + lcol];
#pragma unroll
                        for (int v = 0; v < 4; ++v) {
                            int wrow = mm * 16 + lg * 4 + v;
                            scr[wrow * 64 + (((lcol >> 3) ^ (wrow & 7)) << 3) + (lcol & 7)] =
                                f2bf(acc[mi][ni][v] + bb);
                        }
                    }
                }
                asm volatile("s_waitcnt lgkmcnt(0)" ::: "memory");
#pragma unroll
                for (int rr = 0; rr < 4; ++rr) {
                    int lrow = rr * 8 + (lane >> 3);
                    int chunk = lane & 7;
                    uint4 u = *(const uint4*)&scr[lrow * 64 + ((chunk ^ (lrow & 7)) << 3)];
                    int grow = row0 + wm * 64 + h * 32 + lrow;
                    *(uint4*)(C + (size_t)grow * DATT + cb0 + chunk * 8) = u;
                }
                asm volatile("s_waitcnt lgkmcnt(0)" ::: "memory");
            }
        } else {
            // V: gelu + transposed out C2[(zz*DHID + hid)*S + s]; transpose by hid halves
            unsigned short* C = (unsigned short*)Cp2;
            int zz = row0 >> 11;
            int sb0 = (row0 & 2047) + wm * 64;
            int hb0 = (col0 & 1023) + wn * 64;
#pragma unroll
            for (int h = 0; h < 2; ++h) {
#pragma unroll
                for (int nn = 0; nn < 2; ++nn) {
                    int ni = h * 2 + nn;
                    int lcol = nn * 16 + lr;                      // local hid 0..31
                    float bb = b2[hb0 + h * 32 + lcol];
#pragma unroll
                    for (int mi = 0; mi < 4; ++mi)
#pragma unroll
                        for (int v = 0; v < 4; ++v) {
                            int lrow = mi * 16 + lg * 4 + v;      // local s 0..63
                            float xv = acc[mi][ni][v] + bb;
                            xv = 0.5f * xv * (1.0f + erff(xv * 0.70710678118654752f));
                            scr[lcol * 64 + (((lrow >> 3) ^ (lcol & 7)) << 3) + (lrow & 7)] = f2bf(xv);
                        }
                }
                asm volatile("s_waitcnt lgkmcnt(0)" ::: "memory");
#pragma unroll
                for (int rr = 0; rr < 4; ++rr) {
                    int lhid = rr * 8 + (lane >> 3);              // 0..31
                    int chunk = lane & 7;
                    uint4 u = *(const uint4*)&scr[lhid * 64 + ((chunk ^ (lhid & 7)) << 3)];
                    int ghid = hb0 + h * 32 + lhid;
                    *(uint4*)(C + ((size_t)zz * DHID + ghid) * S_ + sb0 + chunk * 8) = u;
                }
                asm volatile("s_waitcnt lgkmcnt(0)" ::: "memory");
            }
        }
    } else {  // EPI == 4: e = bit ? 0 : exp(acc*scale), coalesced via transpose
        unsigned short* C = (unsigned short*)Cp + (size_t)cStride * z;
        const unsigned* mb = mbits + (size_t)z * (S_ * S_ / 32);
        const int wbase = (col0 + wn * 64) >> 5;
#pragma unroll
        for (int h = 0; h < 2; ++h) {
#pragma unroll
            for (int mm = 0; mm < 2; ++mm) {
                int mi = h * 2 + mm;
#pragma unroll
                for (int v = 0; v < 4; ++v) {
                    int row = row0 + wm * 64 + mi * 16 + lg * 4 + v;
                    unsigned w0 = mb[(size_t)row * (S_ / 32) + wbase];
                    unsigned w1 = mb[(size_t)row * (S_ / 32) + wbase + 1];
                    int wrow = mm * 16 + lg * 4 + v;
#pragma unroll
                    for (int ni = 0; ni < 4; ++ni) {
                        int lcol = ni * 16 + lr;
                        unsigned wsel = (ni & 2) ? w1 : w0;
                        float ev = ((wsel >> ((ni & 1) * 16 + lr)) & 1)
                                 ? 0.0f : __expf(acc[mi][ni][v] * scale);
                        scr[wrow * 64 + (((lcol >> 3) ^ (wrow & 7)) << 3) + (lcol & 7)] = f2bf(ev);
                    }
                }
            }
            asm volatile("s_waitcnt lgkmcnt(0)" ::: "memory");
#pragma unroll
            for (int rr = 0; rr < 4; ++rr) {
                int lrow = rr * 8 + (lane >> 3);
                int chunk = lane & 7;
                uint4 u = *(const uint4*)&scr[lrow * 64 + ((chunk ^ (lrow & 7)) << 3)];
                int grow = row0 + wm * 64 + h * 32 + lrow;
                *(uint4*)(C + (size_t)grow * ldc + col0 + wn * 64 + chunk * 8) = u;
            }
            asm volatile("s_waitcnt lgkmcnt(0)" ::: "memory");
        }
    }
}

// ================== 128^2 dbuf GEMM (R3-proven) + chunked swizzle ==================
// EPI: 6 fused QKV, 2 fp32 scale+mask, 3 fp32, 5 fp32*invs[row]
template<int AMODE, int EPI>
__global__ __launch_bounds__(256)
void gemm_k(const void* __restrict__ Ap, const unsigned short* __restrict__ Bp,
            const float* __restrict__ b0, const float* __restrict__ b1,
            const float* __restrict__ b2, const int* __restrict__ maskp,
            void* __restrict__ Cp, void* __restrict__ Cp2,
            int K, int lda, int ldb, int ldc,
            long aStride, long bStride, long cStride, long mStride, float scale)
{
    __shared__ __align__(16) unsigned short sh[2][2][128][64];
    int bx, by, z;
    xmap(bx, by, z);
    const int tid  = threadIdx.x;
    const int row0 = by * 128;
    const int col0 = bx * 128;
    const int wave = tid >> 6, lane = tid & 63;
    const int lr = lane & 15, lg = lane >> 4;
    const int wm = (wave >> 1) * 64, wn = (wave & 1) * 64;
    const unsigned short* Bb = Bp + (size_t)bStride * z;
    f32x4 acc[4][4] = {};
    const int nt = K >> 6;
    auto stage = [&](int b, int k0) {
        if (AMODE == 0) {
            const unsigned short* A = (const unsigned short*)Ap + (size_t)aStride * z;
#pragma unroll
            for (int q = 0; q < 4; ++q) {
                int c = q * 256 + tid;
                int row = c >> 3, j = c & 7;
                gld16((const char*)(A + (size_t)(row0 + row) * lda + k0) + ((j ^ (row & 7)) << 4),
                      (char*)&sh[b][0][0][0] + ((q * 256 + (tid & 192)) << 4));
            }
        } else {
            const float* A = (const float*)Ap + (size_t)aStride * z;
#pragma unroll
            for (int q = 0; q < 4; ++q) {
                int c = q * 256 + tid;
                int row = c >> 3, j = c & 7;
                const float* src = A + (size_t)(row0 + row) * lda + k0 + ((j ^ (row & 7)) << 3);
                float4 v0 = *(const float4*)src;
                float4 v1 = *(const float4*)(src + 4);
                uint4 p;
                p.x = (unsigned)f2bf(v0.x) | ((unsigned)f2bf(v0.y) << 16);
                p.y = (unsigned)f2bf(v0.z) | ((unsigned)f2bf(v0.w) << 16);
                p.z = (unsigned)f2bf(v1.x) | ((unsigned)f2bf(v1.y) << 16);
                p.w = (unsigned)f2bf(v1.z) | ((unsigned)f2bf(v1.w) << 16);
                *(uint4*)((char*)&sh[b][0][0][0] + ((size_t)c << 4)) = p;
            }
        }
#pragma unroll
        for (int q = 0; q < 4; ++q) {
            int c = q * 256 + tid;
            int row = c >> 3, j = c & 7;
            gld16((const char*)(Bb + (size_t)(col0 + row) * ldb + k0) + ((j ^ (row & 7)) << 4),
                  (char*)&sh[b][1][0][0] + ((q * 256 + (tid & 192)) << 4));
        }
    };
    stage(0, 0);
    __syncthreads();
    int cur = 0;
    for (int t = 0; t < nt; ++t) {
        if (t + 1 < nt) stage(cur ^ 1, (t + 1) << 6);
        const char* baseA = (const char*)&sh[cur][0][0][0];
        const char* baseB = (const char*)&sh[cur][1][0][0];
        bf16x8 af[2][4], bfv[2][4];
#pragma unroll
        for (int s = 0; s < 2; ++s)
#pragma unroll
            for (int i = 0; i < 4; ++i) {
                int ra = wm + i * 16 + lr;
                af[s][i]  = *(const bf16x8*)(baseA + ra * 128 + ((((s << 2) | lg) ^ (ra & 7)) << 4));
                int rb = wn + i * 16 + lr;
                bfv[s][i] = *(const bf16x8*)(baseB + rb * 128 + ((((s << 2) | lg) ^ (rb & 7)) << 4));
            }
#pragma unroll
        for (int s = 0; s < 2; ++s)
#pragma unroll
            for (int mi = 0; mi < 4; ++mi)
#pragma unroll
                for (int ni = 0; ni < 4; ++ni)
                    acc[mi][ni] = __builtin_amdgcn_mfma_f32_16x16x32_bf16(af[s][mi], bfv[s][ni], acc[mi][ni], 0, 0, 0);
        if (t + 1 < nt) __syncthreads();
        cur ^= 1;
    }
    if (EPI == 6) {
        int w = col0 >> 10;
        int cb = (col0 & 1023) + wn;
        if (w < 2) {
            unsigned short* C = (unsigned short*)Cp + (size_t)w * ((size_t)B_ * S_ * DATT);
            const float* bias = w ? b1 : b0;
#pragma unroll
            for (int mi = 0; mi < 4; ++mi)
#pragma unroll
                for (int ni = 0; ni < 4; ++ni) {
                    int col = cb + ni * 16 + lr;
                    float bb = bias[col];
                    int rowb = row0 + wm + mi * 16 + lg * 4;
#pragma unroll
                    for (int v = 0; v < 4; ++v)
                        C[(size_t)(rowb + v) * DATT + col] = f2bf(acc[mi][ni][v] + bb);
                }
        } else {
            unsigned short* C = (unsigned short*)Cp2;
            int zz = row0 >> 11;
            int sb = (row0 & 2047) + wm;
#pragma unroll
            for (int mi = 0; mi < 4; ++mi)
#pragma unroll
                for (int ni = 0; ni < 4; ++ni) {
                    int col = cb + ni * 16 + lr;
                    float bb = b2[col];
                    unsigned short r[4];
#pragma unroll
                    for (int v = 0; v < 4; ++v) {
                        float xv = acc[mi][ni][v] + bb;
                        xv = 0.5f * xv * (1.0f + erff(xv * 0.70710678118654752f));
                        r[v] = f2bf(xv);
                    }
                    uint2 o;
                    o.x = (unsigned)r[0] | ((unsigned)r[1] << 16);
                    o.y = (unsigned)r[2] | ((unsigned)r[3] << 16);
                    *(uint2*)(C + ((size_t)zz * DHID + col) * S_ + sb + mi * 16 + lg * 4) = o;
                }
        }
    } else if (EPI == 5) {
        float* C = (float*)Cp + (size_t)cStride * z;
        const float* invs = b0 + (size_t)z * S_;
#pragma unroll
        for (int mi = 0; mi < 4; ++mi)
#pragma unroll
            for (int ni = 0; ni < 4; ++ni) {
                int col = col0 + wn + ni * 16 + lr;
                int rowb = row0 + wm + mi * 16 + lg * 4;
#pragma unroll
                for (int v = 0; v < 4; ++v)
                    C[(size_t)(rowb + v) * ldc + col] = acc[mi][ni][v] * invs[rowb + v];
            }
    } else {
        float* C = (float*)Cp + (size_t)cStride * z;
        const int* mp = (EPI == 2) ? (maskp + (size_t)mStride * z) : nullptr;
#pragma unroll
        for (int mi = 0; mi < 4; ++mi)
#pragma unroll
            for (int ni = 0; ni < 4; ++ni) {
                int col = col0 + wn + ni * 16 + lr;
                int rowb = row0 + wm + mi * 16 + lg * 4;
#pragma unroll
                for (int v = 0; v < 4; ++v) {
                    float val = acc[mi][ni][v];
                    if (EPI == 2) val = val * scale + (float)mp[(size_t)(rowb + v) * ldc + col] * (-1e9f);
                    C[(size_t)(rowb + v) * ldc + col] = val;
                }
            }
    }
}

// ------- merged rownorm: read e once -> write invs + attn fp32 -------
__global__ __launch_bounds__(256)
void rownormM_k(const unsigned short* __restrict__ e, float* __restrict__ attn,
                float* __restrict__ invs)
{
    const int row = blockIdx.x;
    const int tid = threadIdx.x;
    uint4 u = ((const uint4*)(e + (size_t)row * S_))[tid];
    float f[8];
    f[0] = bf2f(u.x & 0xffffu); f[1] = bf2f(u.x >> 16);
    f[2] = bf2f(u.y & 0xffffu); f[3] = bf2f(u.y >> 16);
    f[4] = bf2f(u.z & 0xffffu); f[5] = bf2f(u.z >> 16);
    f[6] = bf2f(u.w & 0xffffu); f[7] = bf2f(u.w >> 16);
    float s = ((f[0] + f[1]) + (f[2] + f[3])) + ((f[4] + f[5]) + (f[6] + f[7]));
#pragma unroll
    for (int o = 32; o; o >>= 1) s += __shfl_xor(s, o);
    __shared__ float red[4];
    if ((tid & 63) == 0) red[tid >> 6] = s;
    __syncthreads();
    s = (red[0] + red[1]) + (red[2] + red[3]);
    float inv = 1.0f / s;
    float* p = attn + (size_t)row * S_;
    ((float4*)p)[tid * 2]     = make_float4(f[0] * inv, f[1] * inv, f[2] * inv, f[3] * inv);
    ((float4*)p)[tid * 2 + 1] = make_float4(f[4] * inv, f[5] * inv, f[6] * inv, f[7] * inv);
    if (tid == 0) invs[row] = inv;
}

// ---------------- two-pass rownorm (mid tier) ----------------
template<bool WRITEATTN>
__global__ __launch_bounds__(256)
void rownorm_k(const unsigned short* __restrict__ e, float* __restrict__ attn,
               float* __restrict__ invs)
{
    const int row = blockIdx.x;
    const int tid = threadIdx.x;
    uint4 u = ((const uint4*)(e + (size_t)row * S_))[tid];
    float f[8];
    f[0] = bf2f(u.x & 0xffffu); f[1] = bf2f(u.x >> 16);
    f[2] = bf2f(u.y & 0xffffu); f[3] = bf2f(u.y >> 16);
    f[4] = bf2f(u.z & 0xffffu); f[5] = bf2f(u.z >> 16);
    f[6] = bf2f(u.w & 0xffffu); f[7] = bf2f(u.w >> 16);
    float s = ((f[0] + f[1]) + (f[2] + f[3])) + ((f[4] + f[5]) + (f[6] + f[7]));
#pragma unroll
    for (int o = 32; o; o >>= 1) s += __shfl_xor(s, o);
    __shared__ float red[4];
    if ((tid & 63) == 0) red[tid >> 6] = s;
    __syncthreads();
    s = (red[0] + red[1]) + (red[2] + red[3]);
    float inv = 1.0f / s;
    if (WRITEATTN) {
        float* p = attn + (size_t)row * S_;
        ((float4*)p)[tid * 2]     = make_float4(f[0] * inv, f[1] * inv, f[2] * inv, f[3] * inv);
        ((float4*)p)[tid * 2 + 1] = make_float4(f[4] * inv, f[5] * inv, f[6] * inv, f[7] * inv);
    } else {
        if (tid == 0) invs[row] = inv;
    }
}

// ---------------- fallback row softmax ----------------
__global__ __launch_bounds__(256)
void softmax_k(float* __restrict__ attn)
{
    const int row = blockIdx.x;
    float* p = attn + (size_t)row * S_;
    const int tid = threadIdx.x;
    float4 a = ((const float4*)p)[tid * 2];
    float4 b = ((const float4*)p)[tid * 2 + 1];
    float m = fmaxf(fmaxf(fmaxf(a.x, a.y), fmaxf(a.z, a.w)),
                    fmaxf(fmaxf(b.x, b.y), fmaxf(b.z, b.w)));
#pragma unroll
    for (int o = 32; o; o >>= 1) m = fmaxf(m, __shfl_xor(m, o));
    __shared__ float redm[4];
    __shared__ float reds[4];
    if ((tid & 63) == 0) redm[tid >> 6] = m;
    __syncthreads();
    m = fmaxf(fmaxf(redm[0], redm[1]), fmaxf(redm[2], redm[3]));
    float e[8];
    e[0] = expf(a.x - m); e[1] = expf(a.y - m); e[2] = expf(a.z - m); e[3] = expf(a.w - m);
    e[4] = expf(b.x - m); e[5] = expf(b.y - m); e[6] = expf(b.z - m); e[7] = expf(b.w - m);
    float s = e[0] + e[1] + e[2] + e[3] + e[4] + e[5] + e[6] + e[7];
#pragma unroll
    for (int o = 32; o; o >>= 1) s += __shfl_xor(s, o);
    if ((tid & 63) == 0) reds[tid >> 6] = s;
    __syncthreads();
    s = reds[0] + reds[1] + reds[2] + reds[3];
    float inv = 1.0f / s;
    ((float4*)p)[tid * 2]     = make_float4(e[0] * inv, e[1] * inv, e[2] * inv, e[3] * inv);
    ((float4*)p)[tid * 2 + 1] = make_float4(e[4] * inv, e[5] * inv, e[6] * inv, e[7] * inv);
}

extern "C" void kernel_launch(void* const* d_in, const int* in_sizes, int n_in,
                              void* d_out, int out_size, void* d_ws, size_t ws_size,
                              hipStream_t stream)
{
    const float* x    = (const float*)d_in[0];
    const int*   mask = (const int*)d_in[1];
    const float* Wq   = (const float*)d_in[2];
    const float* bq   = (const float*)d_in[3];
    const float* Wk   = (const float*)d_in[4];
    const float* bk   = (const float*)d_in[5];
    const float* Wv   = (const float*)d_in[6];
    const float* bv   = (const float*)d_in[7];

    float* ctx  = (float*)d_out;                       // [B,S,DHID] fp32
    float* attn = ctx + (size_t)B_ * S_ * DHID;        // [B,S,S]    fp32

    unsigned short* Qb = (unsigned short*)ctx;                 // ctx region scratch
    unsigned short* Kb = Qb + (size_t)B_ * S_ * DATT;
    unsigned short* Xb = (unsigned short*)attn;                // attn region scratch
    unsigned short* Wb = Xb + (size_t)B_ * S_ * DIN;

    const size_t eElems  = (size_t)B_ * S_ * S_;
    const size_t mWords  = eElems / 32;
    const size_t wvElems = (size_t)B_ * DHID * S_;

    size_t needFast = eElems * 2 + (size_t)B_ * S_ * 4 + mWords * 4 + wvElems * 2 + 256;
    size_t needMid  = eElems * 2 + (size_t)B_ * S_ * 4 + mWords * 4 + 256;

    dim3 blk(256), blk5(512);

    if (ws_size >= needFast) {
        unsigned short* e    = (unsigned short*)d_ws;                 // 33.55 MB
        float*          invs = (float*)(e + eElems);                  // 32 KB
        unsigned*       mb   = (unsigned*)(invs + (size_t)B_ * S_);   // 2 MB
        unsigned short* WVbT = (unsigned short*)(mb + mWords);        // 16.78 MB

        prep_k<<<dim3(6912), blk, 0, stream>>>(x, Xb, Wq, Wk, Wv, Wb, mask, mb);
        // fused QKV (256x128 tile): [8192,3072] = Xb @ Wb^T (+bias); V gelu+T -> WVbT(ws)
        gemmS_k<6><<<dim3(24, 32, 1), blk5, 0, stream>>>(
            Xb, Wb, bq, bk, bv, nullptr, Qb, WVbT,
            DIN, DIN, DIN, 0, 0, 0, 0, 1.0f);
        // e = exp(QK^T/32), bitmask -> 0, bf16
        gemmS_k<4><<<dim3(16, 8, 4), blk5, 0, stream>>>(
            Qb, Kb, nullptr, nullptr, nullptr, mb, e, nullptr,
            DATT, DATT, DATT, S_,
            (long)S_ * DATT, (long)S_ * DATT, (long)S_ * S_, 0.03125f);
        // merged: invs + attn fp32 (Xb/Wb dead; WVbT safe in ws)
        rownormM_k<<<dim3(B_ * S_), blk, 0, stream>>>(e, attn, invs);
        // ctx = (e @ WV) * inv_rowsum (over Qb/Kb region)
        gemm_k<0, 5><<<dim3(8, 16, 4), blk, 0, stream>>>(
            e, WVbT, invs, nullptr, nullptr, nullptr, ctx, nullptr,
            S_, S_, S_, DHID,
            (long)S_ * S_, (long)DHID * S_, (long)S_ * DHID, 0, 1.0f);
    } else if (ws_size >= needMid) {
        unsigned short* e    = (unsigned short*)d_ws;
        float*          invs = (float*)(e + eElems);
        unsigned*       mb   = (unsigned*)(invs + (size_t)B_ * S_);
        unsigned short* WVbT = Wb + (size_t)3 * DIN * DATT;           // attn region

        prep_k<<<dim3(6912), blk, 0, stream>>>(x, Xb, Wq, Wk, Wv, Wb, mask, mb);
        gemmS_k<6><<<dim3(24, 32, 1), blk5, 0, stream>>>(
            Xb, Wb, bq, bk, bv, nullptr, Qb, WVbT,
            DIN, DIN, DIN, 0, 0, 0, 0, 1.0f);
        gemmS_k<4><<<dim3(16, 8, 4), blk5, 0, stream>>>(
            Qb, Kb, nullptr, nullptr, nullptr, mb, e, nullptr,
            DATT, DATT, DATT, S_,
            (long)S_ * DATT, (long)S_ * DATT, (long)S_ * S_, 0.03125f);
        rownorm_k<false><<<dim3(B_ * S_), blk, 0, stream>>>(e, nullptr, invs);
        gemm_k<0, 5><<<dim3(8, 16, 4), blk, 0, stream>>>(
            e, WVbT, invs, nullptr, nullptr, nullptr, ctx, nullptr,
            S_, S_, S_, DHID,
            (long)S_ * S_, (long)DHID * S_, (long)S_ * DHID, 0, 1.0f);
        rownorm_k<true><<<dim3(B_ * S_), blk, 0, stream>>>(e, attn, nullptr);
    } else {
        // slow tier: no ws assumptions beyond WVw
        unsigned short* WVw = (unsigned short*)d_ws;
        prep_k<<<dim3(4864), blk, 0, stream>>>(x, Xb, Wq, Wk, Wv, Wb, mask, nullptr);
        gemm_k<0, 6><<<dim3(24, 64, 1), blk, 0, stream>>>(
            Xb, Wb, bq, bk, bv, nullptr, Qb, WVw,
            DIN, DIN, DIN, 0, 0, 0, 0, 0, 1.0f);
        gemm_k<0, 2><<<dim3(16, 16, 4), blk, 0, stream>>>(
            Qb, Kb, nullptr, nullptr, nullptr, mask, attn, nullptr,
            DATT, DATT, DATT, S_,
            (long)S_ * DATT, (long)S_ * DATT, (long)S_ * S_, (long)S_ * S_, 0.03125f);
        softmax_k<<<dim3(B_ * S_), blk, 0, stream>>>(attn);
        gemm_k<1, 3><<<dim3(8, 16, 4), blk, 0, stream>>>(
            attn, WVw, nullptr, nullptr, nullptr, nullptr, ctx, nullptr,
            S_, S_, S_, DHID,
            (long)S_ * S_, (long)DHID * S_, (long)S_ * DHID, 0, 1.0f);
    }
}